// Round 1
// baseline (216.837 us; speedup 1.0000x reference)
//
#include <hip/hip_runtime.h>

// Trilinear grid_sample (align_corners=False, zeros padding) over a 128^3
// BINARY grid, 8.4M random points.
//
// R7: promote the byte-table gather path to PRIMARY.
//  Theory: the R6 LDS-slab kernel (81 µs) is structurally bound by
//  (a) 133KB LDS -> 1 block/CU, barrier-drained slab fills,
//  (b) 2-pass divergence (every j-body runs in both passes),
//  (c) 8 random-address LDS words/point -> unavoidable bank conflicts.
//  The 129^3 byte table (2.15 MB, fits per-XCD 4MB L2) collapses the whole
//  2x2x2 neighborhood into ONE random byte load per point: no LDS, no
//  barriers, no pass divergence, full occupancy. Streaming coords/out are
//  marked nontemporal so they don't evict the table from L2.
//  Slab path retained as fallback for small-workspace configs.

typedef float fx4 __attribute__((ext_vector_type(4)));
typedef unsigned int u32;
typedef unsigned int ux4 __attribute__((ext_vector_type(4)));
typedef unsigned long long u64;

constexpr int GS = 128;
constexpr size_t MASK_BYTES = (size_t)GS * GS * GS / 8;   // 256 KB
// slab path LDS: pass B needs 33280 words + 1 pad
constexpr int SLAB_WORDS = 33281;
constexpr size_t SLAB_LDS = (size_t)SLAB_WORDS * 4;       // 133,124 B

// byte-table path
constexpr int TD = GS + 1;                                 // 129
constexpr size_t TBL_BYTES = (size_t)TD * TD * TD;         // 2,146,689 B
constexpr size_t TBL_OFF   = (MASK_BYTES + 63) & ~(size_t)63;
constexpr size_t WS_FB     = TBL_OFF + TBL_BYTES;          // ~2.4 MB

// ---------------------------------------------------------- bitpack ------
__global__ __launch_bounds__(256)
void bitpack_kernel(const float* __restrict__ grid, u64* __restrict__ mask) {
    int gid = blockIdx.x * blockDim.x + threadIdx.x;   // 128^3 threads
    float v = grid[gid];
    u64 m = __ballot(v != 0.0f);
    if ((threadIdx.x & 63) == 0) mask[gid >> 6] = m;
}

// ------------------------------------------------- byte-table build ------
__device__ __forceinline__ unsigned bit_at(u64 lo, u64 hi, int xi) {
    if ((unsigned)xi >= 128u) return 0u;
    u64 w = (xi < 64) ? lo : hi;
    return (unsigned)((w >> (xi & 63)) & 1ull);
}

__global__ __launch_bounds__(256)
void table_kernel(const u64* __restrict__ mask, unsigned char* __restrict__ tbl) {
    int i = blockIdx.x * blockDim.x + threadIdx.x;
    if (i >= (int)TBL_BYTES) return;
    int x = i % TD;                   // consecutive threads share (z,y) rows
    int t = i / TD;                   // -> mask reads are L1-broadcast
    int y = t % TD;
    int z = t / TD;
    int x0 = x - 1;
    unsigned byte = 0u;
#pragma unroll
    for (int dz = 0; dz < 2; ++dz) {
#pragma unroll
        for (int dy = 0; dy < 2; ++dy) {
            int yi = y - 1 + dy, zi = z - 1 + dz;
            u64 lo = 0ull, hi = 0ull;
            if (((unsigned)yi < 128u) & ((unsigned)zi < 128u)) {
                int r = (zi * 128 + yi) * 2;
                lo = mask[r];
                hi = mask[r + 1];
            }
            int kk = dy * 2 + dz * 4;
            byte |= (bit_at(lo, hi, x0) << kk) | (bit_at(lo, hi, x0 + 1) << (kk + 1));
        }
    }
    tbl[i] = (unsigned char)byte;
}

// ------------------------------------------------- primary sampler -------
// One random L2-resident byte load per point. 8 points/thread.
__global__ __launch_bounds__(256)
void sample_packed(const unsigned char* __restrict__ tbl,
                   const float* __restrict__ coords,
                   float* __restrict__ out, int nt) {
    int t = blockIdx.x * blockDim.x + threadIdx.x;
    if (t >= nt) return;
    const fx4* c4 = (const fx4*)coords;
    fx4 q[6];
#pragma unroll
    for (int j = 0; j < 6; ++j) q[j] = __builtin_nontemporal_load(&c4[6 * t + j]);
    const float* f = (const float*)q;
    float wxa[8], wya[8], wza[8];
    int addr[8];
#pragma unroll
    for (int i = 0; i < 8; ++i) {
        float ix = fmaf(f[3 * i + 0], 64.0f, 63.5f);   // ((x+1)*128-1)/2
        float iy = fmaf(f[3 * i + 1], 64.0f, 63.5f);
        float iz = fmaf(f[3 * i + 2], 64.0f, 63.5f);
        float fx = floorf(ix), fy = floorf(iy), fz = floorf(iz);
        wxa[i] = ix - fx; wya[i] = iy - fy; wza[i] = iz - fz;
        int xb = (int)fx + 1, yb = (int)fy + 1, zb = (int)fz + 1;  // [0,128]
        addr[i] = (zb * TD + yb) * TD + xb;
    }
    unsigned bytes[8];
#pragma unroll
    for (int i = 0; i < 8; ++i) bytes[i] = (unsigned)tbl[addr[i]];  // 8 gathers in flight
    float o[8];
#pragma unroll
    for (int i = 0; i < 8; ++i) {
        unsigned byte = bytes[i];
        float wx = wxa[i], wy = wya[i], wz = wza[i];
        float v0 = (float)( byte       & 1u);
        float v1 = (float)((byte >> 1) & 1u);
        float v2 = (float)((byte >> 2) & 1u);
        float v3 = (float)((byte >> 3) & 1u);
        float v4 = (float)((byte >> 4) & 1u);
        float v5 = (float)((byte >> 5) & 1u);
        float v6 = (float)((byte >> 6) & 1u);
        float v7 = (float)((byte >> 7) & 1u);
        float c00 = v0 + wx * (v1 - v0);
        float c10 = v2 + wx * (v3 - v2);
        float c01 = v4 + wx * (v5 - v4);
        float c11 = v6 + wx * (v7 - v6);
        float c0  = c00 + wy * (c10 - c00);
        float c1  = c01 + wy * (c11 - c01);
        o[i] = c0 + wz * (c1 - c0);
    }
    fx4* o4 = (fx4*)out;
    fx4 r0 = {o[0], o[1], o[2], o[3]};
    fx4 r1 = {o[4], o[5], o[6], o[7]};
    __builtin_nontemporal_store(r0, &o4[2 * t + 0]);
    __builtin_nontemporal_store(r1, &o4[2 * t + 1]);
}

// ------------------------------------------------- fallback: LDS slab ----
__global__ __launch_bounds__(1024, 4)
void sample_2p(const u32* __restrict__ mask32,
               const float* __restrict__ coords,
               float* __restrict__ out) {
    extern __shared__ u32 lds[];
    const int tid = threadIdx.x;
    const int T = blockIdx.x * 1024 + tid;
    const fx4* c4 = (const fx4*)coords;
    fx4 q[6];
#pragma unroll
    for (int j = 0; j < 6; ++j) q[j] = c4[6 * T + j];
    const float* f = (const float*)q;

    u32 pack1[8];
    u32 AM = 0;
    float wx[8], wy[8], wz[8], o[8];
#pragma unroll
    for (int j = 0; j < 8; ++j) {
        float ix = fmaf(f[3 * j + 0], 64.0f, 63.5f);
        float iy = fmaf(f[3 * j + 1], 64.0f, 63.5f);
        float iz = fmaf(f[3 * j + 2], 64.0f, 63.5f);
        float fx = floorf(ix), fy = floorf(iy), fz = floorf(iz);
        float w0 = ix - fx;
        wy[j] = iy - fy; wz[j] = iz - fz;
        int x0 = (int)fx, y0 = (int)fy, z0 = (int)fz;  // [-1,127]
        int zb = z0 + 1;                               // [0,128]
        bool flip = (x0 < 0);
        wx[j] = flip ? 1.0f - w0 : w0;
        int xc = flip ? 0 : x0;
        int sft = xc & 31;
        u32 xm = ((u32)x0 <= 126u) ? 3u : 1u;
        u32 vy0 = (u32)(y0 >= 0);
        u32 vy1 = (u32)((u32)y0 <= 126u);
        u32 a0 = vy0 ? xm : 0u;
        u32 a1 = vy1 ? xm : 0u;
        u32 am = a0 | (a1 << 2);
        u32 dyf = vy0 & vy1;
        int y0c = y0 < 0 ? 0 : y0;
        int z0c = z0 < 0 ? 0 : z0;
        u32 RA = (u32)(((z0c << 7) + y0c) * 4 + (xc >> 5));
        pack1[j] = RA | ((u32)sft << 16) | ((u32)zb << 21) | (dyf << 29);
        AM |= am << (4 * j);
        o[j] = 0.0f;
    }

#pragma unroll 1
    for (int s = 0; s < 2; ++s) {
        const int base_w = s ? 32256 : 0;
        const int nv4    = s ? 8320 : 8192;
        __syncthreads();
        {
            const ux4* src = (const ux4*)(mask32 + base_w);
            ux4* dst = (ux4*)lds;
            for (int i = tid; i < nv4; i += 1024) dst[i] = src[i];
            if (s && tid == 0) lds[33280] = 0;
        }
        __syncthreads();
#pragma unroll
        for (int j = 0; j < 8; ++j) {
            u32 p1 = pack1[j];
            int zb = (int)((p1 >> 21) & 0xFF);
            if ((zb < 64) != (s == 0)) continue;
            int la  = (int)(p1 & 0xFFFF) - base_w;
            int sft = (int)((p1 >> 16) & 31);
            int dyw = (int)((p1 >> 27) & 4);
            bool edge = s ? (zb == 128) : (zb == 0);
            int dz = edge ? 0 : 512;
            u32 amv = (AM >> (4 * j)) & 15u;
            u32 glo = amv, ghi = amv;
            if (s) ghi = edge ? 0u : amv;
            else   glo = edge ? 0u : amv;
            int l0 = la, l1 = la + dyw, l2 = la + dz, l3 = la + dz + dyw;
            u32 w00 = lds[l0], w01 = lds[l0 + 1];
            u32 w10 = lds[l1], w11 = lds[l1 + 1];
            u32 w20 = lds[l2], w21 = lds[l2 + 1];
            u32 w30 = lds[l3], w31 = lds[l3 + 1];
            u32 t0 = __builtin_amdgcn_alignbit(w01, w00, (u32)sft) & (glo & 3u);
            u32 t1 = __builtin_amdgcn_alignbit(w11, w10, (u32)sft) & ((glo >> 2) & 3u);
            u32 t2 = __builtin_amdgcn_alignbit(w21, w20, (u32)sft) & (ghi & 3u);
            u32 t3 = __builtin_amdgcn_alignbit(w31, w30, (u32)sft) & ((ghi >> 2) & 3u);
            float w = wx[j];
            int b0 = (int)(t0 & 1u), b1 = (int)(t1 & 1u);
            int b2 = (int)(t2 & 1u), b3 = (int)(t3 & 1u);
            float r00 = fmaf(w, (float)((int)(t0 >> 1) - b0), (float)b0);
            float r01 = fmaf(w, (float)((int)(t1 >> 1) - b1), (float)b1);
            float r10 = fmaf(w, (float)((int)(t2 >> 1) - b2), (float)b2);
            float r11 = fmaf(w, (float)((int)(t3 >> 1) - b3), (float)b3);
            float cy0 = fmaf(wy[j], r01 - r00, r00);
            float cy1 = fmaf(wy[j], r11 - r10, r10);
            o[j] = fmaf(wz[j], cy1 - cy0, cy0);
        }
    }
    fx4* o4 = (fx4*)out;
    fx4 r0 = {o[0], o[1], o[2], o[3]};
    fx4 r1 = {o[4], o[5], o[6], o[7]};
    o4[2 * T]     = r0;
    o4[2 * T + 1] = r1;
}

// -------------------------------------------------------------- launch ----
extern "C" void kernel_launch(void* const* d_in, const int* in_sizes, int n_in,
                              void* d_out, int out_size, void* d_ws, size_t ws_size,
                              hipStream_t stream) {
    const float* grid   = (const float*)d_in[0];
    const float* coords = (const float*)d_in[1];
    float* out = (float*)d_out;
    int npts = in_sizes[1] / 3;                          // 8,388,608
    int vox = GS * GS * GS;

    u64* mask = (u64*)d_ws;                              // 256 KB @ offset 0

    if (ws_size >= WS_FB && (npts & 7) == 0) {
        // PRIMARY: byte-table path. One L2-resident byte gather per point.
        unsigned char* tbl = (unsigned char*)d_ws + TBL_OFF;
        bitpack_kernel<<<vox / 256, 256, 0, stream>>>(grid, mask);
        table_kernel<<<(int)((TBL_BYTES + 255) / 256), 256, 0, stream>>>(mask, tbl);
        int nt = npts / 8;
        sample_packed<<<(nt + 255) / 256, 256, 0, stream>>>(tbl, coords, out, nt);
        return;
    }

    // FALLBACK: 2-pass LDS slab (R6 path).
    (void)hipFuncSetAttribute((const void*)sample_2p,
                              hipFuncAttributeMaxDynamicSharedMemorySize,
                              (int)SLAB_LDS);
    int nb = 0;
    hipError_t oe = hipOccupancyMaxActiveBlocksPerMultiprocessor(
        &nb, sample_2p, 1024, SLAB_LDS);
    bool slab_ok = (oe == hipSuccess) && (nb >= 1) && (ws_size >= MASK_BYTES) &&
                   (npts == 1024 * 8192);
    if (slab_ok) {
        bitpack_kernel<<<vox / 256, 256, 0, stream>>>(grid, mask);
        sample_2p<<<1024, 1024, SLAB_LDS, stream>>>((const u32*)mask, coords, out);
    }
}

// Round 2
// 214.966 us; speedup vs baseline: 1.0087x; 1.0087x over previous
//
#include <hip/hip_runtime.h>

// Trilinear grid_sample (align_corners=False, zeros padding) over a 128^3
// BINARY grid, 8.4M random points.
//
// R8: HYBRID kernel — overlap the two structurally-capped paths.
//  Evidence: R7's table-gather = 76 µs, VALUBusy 13%, HBM 19%, 5.6 cyc per
//  scattered request per CU == 180cyc L2-hit latency / ~32 MSHRs: the
//  scattered-miss pipe is hard-capped. R6's LDS slab = 81 µs, LDS+VALU
//  bound with the vector-memory pipe idle. These bind DIFFERENT pipes.
//  One kernel does both halves of the point array concurrently:
//   - slab half (R6 logic): 8 pts/thread via 2-pass LDS bitmask slabs.
//   - gather half (R7 logic): 8 pts/thread via 1 random byte load each,
//     issued in 2 batches of 4 placed after each slab-fill's coalesced
//     loads (vmcnt FIFO: fill waits become counted, never drain gathers),
//     kept in flight across RAW s_barriers (lgkmcnt(0) only — no vmcnt
//     drain, unlike __syncthreads).
//  s-loop fully unrolled so gb[] indexing is static (no scratch).

typedef float fx4 __attribute__((ext_vector_type(4)));
typedef unsigned int u32;
typedef unsigned int ux4 __attribute__((ext_vector_type(4)));
typedef unsigned long long u64;

constexpr int GS = 128;
constexpr size_t MASK_BYTES = (size_t)GS * GS * GS / 8;   // 256 KB
constexpr int SLAB_WORDS = 33281;
constexpr size_t SLAB_LDS = (size_t)SLAB_WORDS * 4;       // 133,124 B

constexpr int TD = GS + 1;                                 // 129
constexpr size_t TBL_BYTES = (size_t)TD * TD * TD;         // 2,146,689 B
constexpr size_t TBL_OFF   = (MASK_BYTES + 63) & ~(size_t)63;
constexpr size_t WS_FB     = TBL_OFF + TBL_BYTES;          // ~2.4 MB

constexpr int NPTS_FULL = 8388608;
constexpr int HGRP = NPTS_FULL / 2 / 8;                    // 524288 groups/half

// ---------------------------------------------------------- bitpack ------
__global__ __launch_bounds__(256)
void bitpack_kernel(const float* __restrict__ grid, u64* __restrict__ mask) {
    int gid = blockIdx.x * blockDim.x + threadIdx.x;   // 128^3 threads
    float v = grid[gid];
    u64 m = __ballot(v != 0.0f);
    if ((threadIdx.x & 63) == 0) mask[gid >> 6] = m;
}

// ------------------------------------------------- byte-table build ------
__device__ __forceinline__ unsigned bit_at(u64 lo, u64 hi, int xi) {
    if ((unsigned)xi >= 128u) return 0u;
    u64 w = (xi < 64) ? lo : hi;
    return (unsigned)((w >> (xi & 63)) & 1ull);
}

__global__ __launch_bounds__(256)
void table_kernel(const u64* __restrict__ mask, unsigned char* __restrict__ tbl) {
    int i = blockIdx.x * blockDim.x + threadIdx.x;
    if (i >= (int)TBL_BYTES) return;
    int x = i % TD;
    int t = i / TD;
    int y = t % TD;
    int z = t / TD;
    int x0 = x - 1;
    unsigned byte = 0u;
#pragma unroll
    for (int dz = 0; dz < 2; ++dz) {
#pragma unroll
        for (int dy = 0; dy < 2; ++dy) {
            int yi = y - 1 + dy, zi = z - 1 + dz;
            u64 lo = 0ull, hi = 0ull;
            if (((unsigned)yi < 128u) & ((unsigned)zi < 128u)) {
                int r = (zi * 128 + yi) * 2;
                lo = mask[r];
                hi = mask[r + 1];
            }
            int kk = dy * 2 + dz * 4;
            byte |= (bit_at(lo, hi, x0) << kk) | (bit_at(lo, hi, x0 + 1) << (kk + 1));
        }
    }
    tbl[i] = (unsigned char)byte;
}

// ------------------------------------------------- HYBRID sampler --------
__global__ __launch_bounds__(1024, 4)
void sample_hybrid(const u32* __restrict__ mask32,
                   const unsigned char* __restrict__ tbl,
                   const float* __restrict__ coords,
                   float* __restrict__ out) {
    extern __shared__ u32 lds[];
    const int tid = threadIdx.x;
    const int Ts = blockIdx.x * 1024 + tid;            // slab group id
    const int Tg = Ts + HGRP;                          // gather group id
    const fx4* c4 = (const fx4*)coords;

    // ---- coords for both halves (nontemporal: protect table/mask in L2)
    fx4 qs[6], qg[6];
#pragma unroll
    for (int j = 0; j < 6; ++j) qs[j] = __builtin_nontemporal_load(&c4[6 * Ts + j]);
#pragma unroll
    for (int j = 0; j < 6; ++j) qg[j] = __builtin_nontemporal_load(&c4[6 * Tg + j]);
    const float* f  = (const float*)qs;
    const float* fg = (const float*)qg;

    // ---- slab prologue (R6, verified)
    u32 pack1[8];
    u32 AM = 0;
    float wx[8], wy[8], wz[8], o[8];
#pragma unroll
    for (int j = 0; j < 8; ++j) {
        float ix = fmaf(f[3 * j + 0], 64.0f, 63.5f);
        float iy = fmaf(f[3 * j + 1], 64.0f, 63.5f);
        float iz = fmaf(f[3 * j + 2], 64.0f, 63.5f);
        float fx = floorf(ix), fy = floorf(iy), fz = floorf(iz);
        float w0 = ix - fx;
        wy[j] = iy - fy; wz[j] = iz - fz;
        int x0 = (int)fx, y0 = (int)fy, z0 = (int)fz;  // [-1,127]
        int zb = z0 + 1;                               // [0,128]
        bool flip = (x0 < 0);
        wx[j] = flip ? 1.0f - w0 : w0;
        int xc = flip ? 0 : x0;
        int sft = xc & 31;
        u32 xm = ((u32)x0 <= 126u) ? 3u : 1u;
        u32 vy0 = (u32)(y0 >= 0);
        u32 vy1 = (u32)((u32)y0 <= 126u);
        u32 a0 = vy0 ? xm : 0u;
        u32 a1 = vy1 ? xm : 0u;
        u32 am = a0 | (a1 << 2);
        u32 dyf = vy0 & vy1;
        int y0c = y0 < 0 ? 0 : y0;
        int z0c = z0 < 0 ? 0 : z0;
        u32 RA = (u32)(((z0c << 7) + y0c) * 4 + (xc >> 5));
        pack1[j] = RA | ((u32)sft << 16) | ((u32)zb << 21) | (dyf << 29);
        AM |= am << (4 * j);
        o[j] = 0.0f;
    }

    u32 gb[8];

    // ---- two slab passes, fully unrolled (static gb indexing)
#pragma unroll
    for (int s = 0; s < 2; ++s) {
        const int base_w = s ? 32256 : 0;              // 63*512
        if (s) {   // protect LDS from pass-A readers before overwrite
            asm volatile("s_waitcnt lgkmcnt(0)" ::: "memory");
            __builtin_amdgcn_s_barrier();
        }
        const ux4* src = (const ux4*)(mask32 + base_w);
        ux4* dst4 = (ux4*)lds;
        // phase 0: 4 coalesced vec4 loads (+ tail for pass B), then stores
        ux4 t0 = src[tid], t1 = src[tid + 1024], t2 = src[tid + 2048], t3 = src[tid + 3072];
        ux4 tt = {0, 0, 0, 0};
        if (s && tid < 128) tt = src[8192 + tid];
        dst4[tid] = t0; dst4[tid + 1024] = t1; dst4[tid + 2048] = t2; dst4[tid + 3072] = t3;
        if (s && tid < 128) dst4[8192 + tid] = tt;
        // phase 1 loads (older than gathers -> counted vmcnt keeps gathers live)
        ux4 t4 = src[tid + 4096], t5 = src[tid + 5120], t6 = src[tid + 6144], t7 = src[tid + 7168];
        asm volatile("" ::: "memory");
        // gather batch s: 4 scattered byte loads; latency hides under j-loop
#pragma unroll
        for (int i = 0; i < 4; ++i) {
            const int p = 4 * s + i;
            float ix = fmaf(fg[3 * p + 0], 64.0f, 63.5f);
            float iy = fmaf(fg[3 * p + 1], 64.0f, 63.5f);
            float iz = fmaf(fg[3 * p + 2], 64.0f, 63.5f);
            int xb = (int)floorf(ix) + 1;
            int yb = (int)floorf(iy) + 1;
            int zb = (int)floorf(iz) + 1;              // [0,128]
            gb[p] = (u32)tbl[(zb * TD + yb) * TD + xb];
        }
        asm volatile("" ::: "memory");
        dst4[tid + 4096] = t4; dst4[tid + 5120] = t5;
        dst4[tid + 6144] = t6; dst4[tid + 7168] = t7;
        if (s && tid == 0) lds[33280] = 0;             // straddle pad
        asm volatile("s_waitcnt lgkmcnt(0)" ::: "memory");
        __builtin_amdgcn_s_barrier();                  // NO vmcnt drain

        // j-loop (R6, verified)
#pragma unroll
        for (int j = 0; j < 8; ++j) {
            u32 p1 = pack1[j];
            int zb = (int)((p1 >> 21) & 0xFF);
            if ((zb < 64) != (s == 0)) continue;       // not this slab
            int la  = (int)(p1 & 0xFFFF) - base_w;
            int sft = (int)((p1 >> 16) & 31);
            int dyw = (int)((p1 >> 27) & 4);
            bool edge = s ? (zb == 128) : (zb == 0);
            int dz = edge ? 0 : 512;
            u32 amv = (AM >> (4 * j)) & 15u;
            u32 glo = amv, ghi = amv;
            if (s) ghi = edge ? 0u : amv;
            else   glo = edge ? 0u : amv;
            int l0 = la, l1 = la + dyw, l2 = la + dz, l3 = la + dz + dyw;
            u32 w00 = lds[l0], w01 = lds[l0 + 1];
            u32 w10 = lds[l1], w11 = lds[l1 + 1];
            u32 w20 = lds[l2], w21 = lds[l2 + 1];
            u32 w30 = lds[l3], w31 = lds[l3 + 1];
            u32 t0b = __builtin_amdgcn_alignbit(w01, w00, (u32)sft) & (glo & 3u);
            u32 t1b = __builtin_amdgcn_alignbit(w11, w10, (u32)sft) & ((glo >> 2) & 3u);
            u32 t2b = __builtin_amdgcn_alignbit(w21, w20, (u32)sft) & (ghi & 3u);
            u32 t3b = __builtin_amdgcn_alignbit(w31, w30, (u32)sft) & ((ghi >> 2) & 3u);
            float w = wx[j];
            int b0 = (int)(t0b & 1u), b1 = (int)(t1b & 1u);
            int b2 = (int)(t2b & 1u), b3 = (int)(t3b & 1u);
            float r00 = fmaf(w, (float)((int)(t0b >> 1) - b0), (float)b0);
            float r01 = fmaf(w, (float)((int)(t1b >> 1) - b1), (float)b1);
            float r10 = fmaf(w, (float)((int)(t2b >> 1) - b2), (float)b2);
            float r11 = fmaf(w, (float)((int)(t3b >> 1) - b3), (float)b3);
            float cy0 = fmaf(wy[j], r01 - r00, r00);
            float cy1 = fmaf(wy[j], r11 - r10, r10);
            o[j] = fmaf(wz[j], cy1 - cy0, cy0);
        }
    }

    // ---- consume gathered bytes (weights recomputed from qg)
    float og[8];
#pragma unroll
    for (int i = 0; i < 8; ++i) {
        float ix = fmaf(fg[3 * i + 0], 64.0f, 63.5f);
        float iy = fmaf(fg[3 * i + 1], 64.0f, 63.5f);
        float iz = fmaf(fg[3 * i + 2], 64.0f, 63.5f);
        float fx = floorf(ix), fy = floorf(iy), fz = floorf(iz);
        float gwx = ix - fx, gwy = iy - fy, gwz = iz - fz;
        unsigned byte = gb[i];
        float v0 = (float)( byte       & 1u);
        float v1 = (float)((byte >> 1) & 1u);
        float v2 = (float)((byte >> 2) & 1u);
        float v3 = (float)((byte >> 3) & 1u);
        float v4 = (float)((byte >> 4) & 1u);
        float v5 = (float)((byte >> 5) & 1u);
        float v6 = (float)((byte >> 6) & 1u);
        float v7 = (float)((byte >> 7) & 1u);
        float c00 = v0 + gwx * (v1 - v0);
        float c10 = v2 + gwx * (v3 - v2);
        float c01 = v4 + gwx * (v5 - v4);
        float c11 = v6 + gwx * (v7 - v6);
        float c0  = c00 + gwy * (c10 - c00);
        float c1  = c01 + gwy * (c11 - c01);
        og[i] = c0 + gwz * (c1 - c0);
    }

    fx4* o4 = (fx4*)out;
    fx4 r0 = {o[0], o[1], o[2], o[3]};
    fx4 r1 = {o[4], o[5], o[6], o[7]};
    fx4 g0 = {og[0], og[1], og[2], og[3]};
    fx4 g1 = {og[4], og[5], og[6], og[7]};
    __builtin_nontemporal_store(r0, &o4[2 * Ts]);
    __builtin_nontemporal_store(r1, &o4[2 * Ts + 1]);
    __builtin_nontemporal_store(g0, &o4[2 * Tg]);
    __builtin_nontemporal_store(g1, &o4[2 * Tg + 1]);
}

// ------------------------------------------------- fallback sampler ------
__global__ __launch_bounds__(256)
void sample_packed(const unsigned char* __restrict__ tbl,
                   const float* __restrict__ coords,
                   float* __restrict__ out, int nt) {
    int t = blockIdx.x * blockDim.x + threadIdx.x;
    if (t >= nt) return;
    const fx4* c4 = (const fx4*)coords;
    fx4 q[6];
#pragma unroll
    for (int j = 0; j < 6; ++j) q[j] = __builtin_nontemporal_load(&c4[6 * t + j]);
    const float* f = (const float*)q;
    float wxa[8], wya[8], wza[8];
    int addr[8];
#pragma unroll
    for (int i = 0; i < 8; ++i) {
        float ix = fmaf(f[3 * i + 0], 64.0f, 63.5f);
        float iy = fmaf(f[3 * i + 1], 64.0f, 63.5f);
        float iz = fmaf(f[3 * i + 2], 64.0f, 63.5f);
        float fx = floorf(ix), fy = floorf(iy), fz = floorf(iz);
        wxa[i] = ix - fx; wya[i] = iy - fy; wza[i] = iz - fz;
        int xb = (int)fx + 1, yb = (int)fy + 1, zb = (int)fz + 1;
        addr[i] = (zb * TD + yb) * TD + xb;
    }
    unsigned bytes[8];
#pragma unroll
    for (int i = 0; i < 8; ++i) bytes[i] = (unsigned)tbl[addr[i]];
    float o[8];
#pragma unroll
    for (int i = 0; i < 8; ++i) {
        unsigned byte = bytes[i];
        float wx = wxa[i], wy = wya[i], wz = wza[i];
        float v0 = (float)( byte       & 1u);
        float v1 = (float)((byte >> 1) & 1u);
        float v2 = (float)((byte >> 2) & 1u);
        float v3 = (float)((byte >> 3) & 1u);
        float v4 = (float)((byte >> 4) & 1u);
        float v5 = (float)((byte >> 5) & 1u);
        float v6 = (float)((byte >> 6) & 1u);
        float v7 = (float)((byte >> 7) & 1u);
        float c00 = v0 + wx * (v1 - v0);
        float c10 = v2 + wx * (v3 - v2);
        float c01 = v4 + wx * (v5 - v4);
        float c11 = v6 + wx * (v7 - v6);
        float c0  = c00 + wy * (c10 - c00);
        float c1  = c01 + wy * (c11 - c01);
        o[i] = c0 + wz * (c1 - c0);
    }
    fx4* o4 = (fx4*)out;
    fx4 r0 = {o[0], o[1], o[2], o[3]};
    fx4 r1 = {o[4], o[5], o[6], o[7]};
    __builtin_nontemporal_store(r0, &o4[2 * t + 0]);
    __builtin_nontemporal_store(r1, &o4[2 * t + 1]);
}

// -------------------------------------------------------------- launch ----
extern "C" void kernel_launch(void* const* d_in, const int* in_sizes, int n_in,
                              void* d_out, int out_size, void* d_ws, size_t ws_size,
                              hipStream_t stream) {
    const float* grid   = (const float*)d_in[0];
    const float* coords = (const float*)d_in[1];
    float* out = (float*)d_out;
    int npts = in_sizes[1] / 3;                          // 8,388,608
    int vox = GS * GS * GS;

    u64* mask = (u64*)d_ws;                              // 256 KB @ offset 0

    if (ws_size >= WS_FB && npts == NPTS_FULL) {
        // PRIMARY: hybrid. Probe 133,124B dynamic LDS legality (capture-safe).
        (void)hipFuncSetAttribute((const void*)sample_hybrid,
                                  hipFuncAttributeMaxDynamicSharedMemorySize,
                                  (int)SLAB_LDS);
        int nb = 0;
        hipError_t oe = hipOccupancyMaxActiveBlocksPerMultiprocessor(
            &nb, sample_hybrid, 1024, SLAB_LDS);
        unsigned char* tbl = (unsigned char*)d_ws + TBL_OFF;
        bitpack_kernel<<<vox / 256, 256, 0, stream>>>(grid, mask);
        table_kernel<<<(int)((TBL_BYTES + 255) / 256), 256, 0, stream>>>(mask, tbl);
        if (oe == hipSuccess && nb >= 1) {
            sample_hybrid<<<512, 1024, SLAB_LDS, stream>>>(
                (const u32*)mask, tbl, coords, out);
        } else {
            int nt = npts / 8;
            sample_packed<<<(nt + 255) / 256, 256, 0, stream>>>(tbl, coords, out, nt);
        }
        return;
    }

    if (ws_size >= WS_FB && (npts & 7) == 0) {
        // FALLBACK: pure byte-table path.
        unsigned char* tbl = (unsigned char*)d_ws + TBL_OFF;
        bitpack_kernel<<<vox / 256, 256, 0, stream>>>(grid, mask);
        table_kernel<<<(int)((TBL_BYTES + 255) / 256), 256, 0, stream>>>(mask, tbl);
        int nt = npts / 8;
        sample_packed<<<(nt + 255) / 256, 256, 0, stream>>>(tbl, coords, out, nt);
    }
}